// Round 8
// baseline (211.938 us; speedup 1.0000x reference)
//
#include <hip/hip_runtime.h>
#include <stdint.h>

typedef unsigned int u32;
typedef unsigned long long u64;

#define N8   130560   // (2176/8)*(3840/8)   = 272*480
#define N16  32640    // (2176/16)*(3840/16) = 136*240
#define N32  8160     // (2176/32)*(3840/32) = 68*120
#define NTOT 171360
#define NTOT4 42840   // NTOT/4
#define TOPK 1000
#define NWORDS 16
#define NBINS 4096
#define BUCKET_SCALE 682.0f
#define LIST_CAP 2048
#define NBLK 168           // ceil(NTOT4/256); <=256 CUs -> co-resident (required for K2 spins)
#define NRED 32            // reducer blocks in K2
#define RANK_BLKS 32       // rank blocks in K2 (64 candidates each)
#define IOU_TASKS (TOPK * NWORDS)   // 16000
#define IOU_BLKS 63
#define NMS_CACHE 256

// workspace layout (bytes). NOTHING is memset: partials/list/mask are fully overwritten
// before being read; meta/nz are zeroed by K1 block 0 (plain stores, dispatch-boundary
// coherent); B-publish uses a 0xC0DE tag that poison (0xAAAAAAAA) can't fake.
#define OFF_PART 0                  // u32[168*4096] = 2.75 MB, part[blk][bin]
#define OFF_RED  2752512            // u32[4096] reduced hist
#define OFF_META 2768896            // u32[64]: [0]=B-publish [1]=listCnt [2]=compactArrive
                                    //          [3]=reduceArrive [56]=iouArrive
#define OFF_NZ   2769152            // u64[16]
#define OFF_LIST 2769280            // u64[2048]
#define OFF_MASK 2785664            // u64[16*1000], transposed: mask[w*1000+i]

// sc1 agent-scope relaxed atomics (L1/L2-bypass, IF-coherent) for same-kernel
// cross-block handoffs. __syncthreads drains vmcnt -> prior sc1 stores are visible
// before any subsequent arrive-RMW (fence-free pattern, validated R6/R7).
__device__ __forceinline__ u32 ald32(const u32* p) {
  return __hip_atomic_load(p, __ATOMIC_RELAXED, __HIP_MEMORY_SCOPE_AGENT);
}
__device__ __forceinline__ u64 ald64(const u64* p) {
  return __hip_atomic_load(p, __ATOMIC_RELAXED, __HIP_MEMORY_SCOPE_AGENT);
}
__device__ __forceinline__ void ast32(u32* p, u32 v) {
  __hip_atomic_store(p, v, __ATOMIC_RELAXED, __HIP_MEMORY_SCOPE_AGENT);
}
__device__ __forceinline__ void ast64(u64* p, u64 v) {
  __hip_atomic_store(p, v, __ATOMIC_RELAXED, __HIP_MEMORY_SCOPE_AGENT);
}

__device__ __forceinline__ u32 bucket_of(float x) {
  u32 b = (u32)(x * BUCKET_SCALE);
  return b > (NBINS - 1) ? (NBINS - 1) : b;
}

__device__ __forceinline__ float4 load_logit4(int v, const float* s8, const float* s16,
                                              const float* s32) {
  int e = v * 4;
  if (e < N8) return ((const float4*)s8)[v];
  if (e < N8 + N16) return ((const float4*)s16)[v - N8 / 4];
  return ((const float4*)s32)[v - (N8 + N16) / 4];
}

__device__ __forceinline__ bool iou_gt04(float4 a, float4 b) {
#pragma clang fp contract(off)
  float areaA = (a.z - a.x) * (a.w - a.y);
  float areaB = (b.z - b.x) * (b.w - b.y);
  float ltx = fmaxf(a.x, b.x);
  float lty = fmaxf(a.y, b.y);
  float rbx = fminf(a.z, b.z);
  float rby = fminf(a.w, b.w);
  float wx = rbx - ltx; wx = wx > 0.0f ? wx : 0.0f;
  float wy = rby - lty; wy = wy > 0.0f ? wy : 0.0f;
  float inter = wx * wy;
  float un = areaA + areaB - inter;
  un = un > 1e-9f ? un : 1e-9f;
  return (inter / un) > 0.4f;
}

__device__ __forceinline__ u64 valid_word(int w, u32 vcnt) {
  int lo = w * 64;
  if ((int)vcnt >= lo + 64) return ~0ull;
  if ((int)vcnt <= lo) return 0ull;
  return (1ull << (vcnt - (u32)lo)) - 1ull;
}

// K1: per-block LDS histogram of positive logits -> plain-stored partial (no zeroing
// needed anywhere: plain stores overwrite poison). Block 0 zeroes meta/nz for K2/K3.
__global__ void __launch_bounds__(256) k_hist(
    const float* __restrict__ s8, const float* __restrict__ s16, const float* __restrict__ s32,
    u32* __restrict__ part, u32* __restrict__ meta, u64* __restrict__ nzWords) {
  __shared__ u32 lh[NBINS];
  int t = threadIdx.x, blk = blockIdx.x;
#pragma unroll
  for (int k = 0; k < 16; ++k) lh[k * 256 + t] = 0;
  __syncthreads();
  int v = blk * 256 + t;
  if (v < NTOT4) {
    float4 x = load_logit4(v, s8, s16, s32);
    if (x.x > 0.0f) atomicAdd(&lh[bucket_of(x.x)], 1u);
    if (x.y > 0.0f) atomicAdd(&lh[bucket_of(x.y)], 1u);
    if (x.z > 0.0f) atomicAdd(&lh[bucket_of(x.z)], 1u);
    if (x.w > 0.0f) atomicAdd(&lh[bucket_of(x.w)], 1u);
  }
  __syncthreads();
#pragma unroll
  for (int k = 0; k < 16; ++k) part[blk * NBINS + k * 256 + t] = lh[k * 256 + t];
  if (blk == 0) {
    if (t < 64) meta[t] = 0;
    if (t < NWORDS) nzWords[t] = 0ull;
  }
}

// K2: fused findB + compact + rank + decode (3 internal spin-flag handoffs, no gbar).
//  stage 1: blocks 0..31 reduce partial-hist slices (parallel: 86 KB each) -> reduced[]
//  stage 2: block 0 assembles hist, suffix-scans, finds B, publishes 0xC0DE0000|B
//  stage 3: all 168 blocks (scores prefetched before the spin) compact via sc1
//  stage 4: blocks 0..31 spin on compact-arrivals==168, then rank (1 wave) + decode -> out
__global__ void __launch_bounds__(256) k_sel(
    const float* __restrict__ s8, const float* __restrict__ s16, const float* __restrict__ s32,
    const float* __restrict__ bb8,  const float* __restrict__ kp8,
    const float* __restrict__ bb16, const float* __restrict__ kp16,
    const float* __restrict__ bb32, const float* __restrict__ kp32,
    const u32* __restrict__ part, u32* red, u32* meta, u64* list,
    float* __restrict__ out) {
  __shared__ __align__(16) char smem[16896];   // hloc 16K+csum overlay / keys 16K
  __shared__ u32 sB, sCnt;
  const int t = threadIdx.x, blk = blockIdx.x;
  const int v = blk * 256 + t;

  // prefetch scores before any spinning
  float4 x = make_float4(-1.f, -1.f, -1.f, -1.f);
  if (v < NTOT4) x = load_logit4(v, s8, s16, s32);

  // ---- stage 1: parallel reduce of 168 partials, 32 blocks x 128 bins ----
  if (blk < NRED) {
    u32* lhs = (u32*)smem;
    int bin = blk * 128 + (t & 127);
    int pp = t >> 7;                 // 0 or 1
    u32 acc = 0;
    for (int p = pp; p < NBLK; p += 2) acc += part[p * NBINS + bin];
    lhs[t] = acc;
    __syncthreads();
    if (t < 128) ast32(&red[blk * 128 + t], lhs[t] + lhs[t + 128]);
    __syncthreads();
    if (t == 0)
      __hip_atomic_fetch_add(&meta[3], 1u, __ATOMIC_RELAXED, __HIP_MEMORY_SCOPE_AGENT);
  }

  // ---- stage 2: block 0 finds B and publishes ----
  // B = max bucket with count(>=B) >= TOPK; 0 if fewer than TOPK positives.
  if (blk == 0) {
    if (t == 0)
      while (ald32(&meta[3]) < (u32)NRED) __builtin_amdgcn_s_sleep(2);
    __syncthreads();
    u32* hloc = (u32*)smem;
    u32* csum = (u32*)(smem + 16384);
#pragma unroll
    for (int k = 0; k < 16; ++k) hloc[k * 256 + t] = ald32(&red[k * 256 + t]);
    __syncthreads();
    u32 sum = 0;
    int base = t * 16;
#pragma unroll
    for (int k = 0; k < 16; ++k) sum += hloc[base + k];
    csum[t] = sum;
    __syncthreads();
    for (int off = 1; off < 256; off <<= 1) {   // inclusive suffix scan
      u32 add = (t + off < 256) ? csum[t + off] : 0u;
      __syncthreads();
      csum[t] += add;
      __syncthreads();
    }
    u32 above = (t < 255) ? csum[t + 1] : 0u;
    if (t == 0 && csum[0] < TOPK) ast32(&meta[0], 0xC0DE0000u);   // B=0
    if (csum[t] >= TOPK && above < TOPK) {      // exactly one thread
      u32 cum = above, Bv = (u32)(t * 16);
      for (int b = t * 16 + 15; b >= t * 16; --b) {
        cum += hloc[b];
        if (cum >= TOPK) { Bv = (u32)b; break; }
      }
      ast32(&meta[0], 0xC0DE0000u | Bv);
    }
    __syncthreads();   // keys[] overlay below must not race hloc reads
  }

  // ---- stage 3: all blocks spin for B, then compact (sc1 list stores) ----
  if (t == 0) {
    u32 pv;
    while (((pv = ald32(&meta[0])) >> 16) != 0xC0DEu) __builtin_amdgcn_s_sleep(2);
    sB = pv & 0xFFFFu;
  }
  __syncthreads();
  const u32 B = sB;
  if (v < NTOT4) {
    float c[4] = {x.x, x.y, x.z, x.w};
#pragma unroll
    for (int j = 0; j < 4; ++j) {
      float xx = c[j];
      if (xx > 0.0f && bucket_of(xx) >= B) {
        u32 pos = atomicAdd(&meta[1], 1u);
        if (pos < LIST_CAP) {
          u32 idx = (u32)(v * 4 + j);
          ast64(&list[pos], ((u64)__float_as_uint(xx) << 32) | (u64)(~idx));
        }
      }
    }
  }
  __syncthreads();   // drain this block's sc1 stores (vmcnt) before arriving
  if (t == 0)
    __hip_atomic_fetch_add(&meta[2], 1u, __ATOMIC_RELAXED, __HIP_MEMORY_SCOPE_AGENT);
  if (blk >= RANK_BLKS) return;

  // ---- stage 4: blocks 0..31: O(n^2) exact rank (desc key = stable top-k) + decode ----
  if (t == 0) {
    while (ald32(&meta[2]) < (u32)NBLK) __builtin_amdgcn_s_sleep(2);
    sCnt = ald32(&meta[1]);
  }
  __syncthreads();
  u32 cnt = sCnt;
  if (cnt > LIST_CAP) cnt = LIST_CAP;
  u64* keys = (u64*)smem;
  for (int j = t; j < LIST_CAP; j += 256) keys[j] = (j < (int)cnt) ? ald64(&list[j]) : 0ull;
  __syncthreads();
  if (t >= 64) return;            // 1 active wave/block: LDS pipe uncontended
  int tid = blk * 64 + t;         // candidate id, 0..2047
  if (tid < (int)cnt) {
    u64 my = keys[tid];
    int rank = 0, j = 0;
    for (; j + 4 <= (int)cnt; j += 4)
      rank += (keys[j] > my) + (keys[j + 1] > my) + (keys[j + 2] > my) + (keys[j + 3] > my);
    for (; j < (int)cnt; ++j) rank += (keys[j] > my);
    if (rank < TOPK) {
      float lx = __uint_as_float((u32)(my >> 32));
      float sc = (float)(1.0 / (1.0 + exp(-(double)lx)));   // sigmoid in f64, round once
      u32 idx = ~((u32)my);
      float4 box;
      float kv[10];
      int p, xq, yq;
      float st;
      const float *bb, *kp;
      if (idx < N8) {
        st = 8.f;  p = (int)idx;              xq = p % 480; yq = p / 480; bb = bb8;  kp = kp8;
      } else if (idx < N8 + N16) {
        st = 16.f; p = (int)idx - N8;         xq = p % 240; yq = p / 240; bb = bb16; kp = kp16;
      } else {
        st = 32.f; p = (int)idx - (N8 + N16); xq = p % 120; yq = p / 120; bb = bb32; kp = kp32;
      }
      float cx = (float)xq * st, cy = (float)yq * st;
      {
#pragma clang fp contract(off)
        float d0 = bb[4 * p + 0] * st;
        float d1 = bb[4 * p + 1] * st;
        float d2 = bb[4 * p + 2] * st;
        float d3 = bb[4 * p + 3] * st;
        box.x = cx - d0; box.y = cy - d1; box.z = cx + d2; box.w = cy + d3;
        for (int q = 0; q < 10; ++q)
          kv[q] = kp[10 * p + q] * st + ((q & 1) ? cy : cx);
      }
      ((float4*)out)[rank] = box;
      out[4000 + rank] = sc;
      for (int q = 0; q < 10; ++q) out[5000 + 10 * rank + q] = kv[q];
    }
  } else if (tid < TOPK) {   // unfilled rows: zero
    ((float4*)out)[tid] = make_float4(0.f, 0.f, 0.f, 0.f);
    out[4000 + tid] = 0.f;
    for (int q = 0; q < 10; ++q) out[5000 + 10 * tid + q] = 0.f;
  }
}

// K3: suppression bitmask (63 blocks) + last-arriver greedy NMS + suppressed-row zeroing.
__global__ void __launch_bounds__(256) k_iou_nms(
    const u32* __restrict__ meta_ro, u32* meta, u64* nzWords, u64* mask, float* out) {
  __shared__ __align__(16) char smem[36864];
  __shared__ int isLast;
  __shared__ u32 sPc[16], sOff17[17];
  __shared__ u64 sRem[NWORDS];
  int t = threadIdx.x;
  int blk = blockIdx.x;

  float4* boxes = (float4*)smem;
  for (int r = t; r < TOPK; r += 256) boxes[r] = ((const float4*)out)[r];
  __syncthreads();
  int task = blk * 256 + t;
  if (task < IOU_TASKS) {
    int w = task / 1000;          // 0..15  (wave-mostly-uniform)
    int i = task - w * 1000;      // 0..999 (consecutive per lane -> coalesced)
    float4 a = boxes[i];
    int bse = w * 64;
    int jend = (bse + 64) < TOPK ? (bse + 64) : TOPK;
    u64 bits = 0;
    for (int j = bse; j < jend; ++j)          // boxes[j] wave-broadcast, conflict-free
      if (j > i && iou_gt04(a, boxes[j])) bits |= 1ull << (j - bse);
    ast64(&mask[(u64)w * 1000 + i], bits);    // coalesced (transposed layout)
    if (bits) atomicOr(&nzWords[i >> 6], 1ull << (i & 63));
  }
  __syncthreads();
  if (t == 0)
    isLast = (__hip_atomic_fetch_add(&meta[56], 1u, __ATOMIC_RELAXED,
                                     __HIP_MEMORY_SCOPE_AGENT) == (u32)(IOU_BLKS - 1));
  __syncthreads();
  if (!isLast) return;

  // ---- last arriver: exact greedy NMS over nonzero-mask rows only ----
  // Rows with empty suppression sets can't change the removed set -> skipping is exact.
  u32 cnt = meta_ro[1];
  if (cnt > LIST_CAP) cnt = LIST_CAP;
  const u32 vcnt = cnt < TOPK ? cnt : TOPK;
  u32* rows = (u32*)smem;             // up to 1000 row ids (4 KB)
  u64* cache = (u64*)(smem + 4096);   // NMS_CACHE x 16 u64 (32 KB)
  u64 nzv = 0;
  if (t < NWORDS) {
    nzv = ald64(&nzWords[t]) & valid_word(t, vcnt);
    sPc[t] = (u32)__popcll(nzv);
  }
  __syncthreads();
  if (t == 0) {
    u32 o = 0;
    for (int w = 0; w < NWORDS; ++w) { sOff17[w] = o; o += sPc[w]; }
    sOff17[16] = o;
  }
  __syncthreads();
  if (t < NWORDS) {           // expand to ascending row list
    u64 m = nzv;
    u32 o = sOff17[t];
    while (m) { int b = __builtin_ctzll(m); m &= m - 1; rows[o++] = (u32)(t * 64 + b); }
  }
  __syncthreads();
  const int S = (int)sOff17[16];
  const int Sc = S < NMS_CACHE ? S : NMS_CACHE;
  for (int idx = t; idx < Sc * NWORDS; idx += 256) {   // parallel mask prefetch -> LDS
    int s = idx >> 4, w = idx & 15;
    cache[s * NWORDS + w] = ald64(&mask[(u64)w * 1000 + rows[s]]);
  }
  __syncthreads();
  if (t < 64) {               // serial greedy chain, LDS-fed; lane<16 owns word `lane`
    u64 remv = 0;
    for (int s = 0; s < S; ++s) {
      u32 row = rows[s];
      int c = (int)(row >> 6), b = (int)(row & 63);
      u64 remc = __shfl(remv, c);
      if (!((remc >> b) & 1ull)) {   // row still alive -> apply its suppression row
        u64 m = 0;
        if (t < NWORDS)
          m = (s < NMS_CACHE) ? cache[s * NWORDS + t] : ald64(&mask[(u64)t * 1000 + row]);
        remv |= m;
      }
    }
    if (t < NWORDS) sRem[t] = valid_word(t, vcnt) & remv;   // rows to zero
  }
  __syncthreads();
  for (int r = t; r < TOPK; r += 256) {
    if ((sRem[r >> 6] >> (r & 63)) & 1ull) {
      ((float4*)out)[r] = make_float4(0.f, 0.f, 0.f, 0.f);
      out[4000 + r] = 0.f;
      for (int q = 0; q < 10; ++q) out[5000 + 10 * r + q] = 0.f;
    }
  }
}

extern "C" void kernel_launch(void* const* d_in, const int* in_sizes, int n_in,
                              void* d_out, int out_size, void* d_ws, size_t ws_size,
                              hipStream_t stream) {
  const float* s8   = (const float*)d_in[1];
  const float* bb8  = (const float*)d_in[2];
  const float* kp8  = (const float*)d_in[3];
  const float* s16  = (const float*)d_in[4];
  const float* bb16 = (const float*)d_in[5];
  const float* kp16 = (const float*)d_in[6];
  const float* s32  = (const float*)d_in[7];
  const float* bb32 = (const float*)d_in[8];
  const float* kp32 = (const float*)d_in[9];

  char* ws = (char*)d_ws;
  u32* part    = (u32*)(ws + OFF_PART);
  u32* red     = (u32*)(ws + OFF_RED);
  u32* meta    = (u32*)(ws + OFF_META);
  u64* nzWords = (u64*)(ws + OFF_NZ);
  u64* list    = (u64*)(ws + OFF_LIST);
  u64* mask    = (u64*)(ws + OFF_MASK);
  float* out   = (float*)d_out;

  k_hist<<<NBLK, 256, 0, stream>>>(s8, s16, s32, part, meta, nzWords);
  k_sel<<<NBLK, 256, 0, stream>>>(s8, s16, s32, bb8, kp8, bb16, kp16, bb32, kp32,
                                  part, red, meta, list, out);
  k_iou_nms<<<IOU_BLKS, 256, 0, stream>>>(meta, meta, nzWords, mask, out);
}

// Round 9
// 193.764 us; speedup vs baseline: 1.0938x; 1.0938x over previous
//
#include <hip/hip_runtime.h>
#include <stdint.h>

typedef unsigned int u32;
typedef unsigned long long u64;

#define N8   130560   // (2176/8)*(3840/8)   = 272*480
#define N16  32640    // (2176/16)*(3840/16) = 136*240
#define N32  8160     // (2176/32)*(3840/32) = 68*120
#define NTOT 171360
#define NTOT4 42840   // NTOT/4
#define TOPK 1000
#define NWORDS 16
#define NBINS 4096
#define BUCKET_SCALE 682.0f
#define LIST_CAP 2048
#define NBLK 168           // ceil(NTOT4/256); <=256 CUs -> co-resident (required for K2 spins)
#define NRED 32            // reducer blocks in K2
#define RANK_BLKS 32       // rank blocks in K2 (64 candidates each)
#define IOU_TASKS (TOPK * NWORDS)   // 16000
#define IOU_BLKS 63
#define NMS_CACHE 256

// meta u32 indices — ONE sync variable per 512 B line (R8 lesson: sharing a coherence
// line between the listCnt RMW stream and 168 pollers serialized ~65us at the IF point)
#define MI_B    0      // B publish: 0xC0DE0000 | B
#define MI_CNT  128    // list count atomic (RMW-only line)
#define MI_RED  256    // reduce arrive counter (RMW-only)
#define MI_REDD 384    // reduce done flag: 0xC0DE
#define MI_CMP  512    // compact arrive counter (RMW-only)
#define MI_CMPD 640    // compact done flag: 0xC0DE0000 | cnt
#define MI_IOU  768    // iou arrive counter (RMW-only, no pollers)
#define META_U32 1024  // 4 KB

// workspace layout (bytes). NOTHING is memset: partials/list/mask fully overwritten
// before read; meta/nz zeroed by K1 block 0 (plain stores, dispatch-boundary coherent);
// publishes use 0xC0DE tags that poison (0xAAAAAAAA) can't fake.
#define OFF_PART 0                  // u32[168*4096] = 2.75 MB, part[blk][bin]
#define OFF_RED  2752512            // u32[4096] reduced hist
#define OFF_META 2768896            // u32[1024]
#define OFF_NZ   2772992            // u64[16]
#define OFF_LIST 2773120            // u64[2048]
#define OFF_MASK 2789504            // u64[16*1000], transposed: mask[w*1000+i]

// sc1 agent-scope relaxed atomics (L1/L2-bypass, IF-coherent) for same-kernel
// cross-block handoffs. __syncthreads drains vmcnt -> prior sc1 stores are visible
// before any subsequent arrive-RMW (fence-free pattern, validated R6-R8).
__device__ __forceinline__ u32 ald32(const u32* p) {
  return __hip_atomic_load(p, __ATOMIC_RELAXED, __HIP_MEMORY_SCOPE_AGENT);
}
__device__ __forceinline__ u64 ald64(const u64* p) {
  return __hip_atomic_load(p, __ATOMIC_RELAXED, __HIP_MEMORY_SCOPE_AGENT);
}
__device__ __forceinline__ void ast32(u32* p, u32 v) {
  __hip_atomic_store(p, v, __ATOMIC_RELAXED, __HIP_MEMORY_SCOPE_AGENT);
}
__device__ __forceinline__ void ast64(u64* p, u64 v) {
  __hip_atomic_store(p, v, __ATOMIC_RELAXED, __HIP_MEMORY_SCOPE_AGENT);
}

__device__ __forceinline__ u32 bucket_of(float x) {
  u32 b = (u32)(x * BUCKET_SCALE);
  return b > (NBINS - 1) ? (NBINS - 1) : b;
}

__device__ __forceinline__ float4 load_logit4(int v, const float* s8, const float* s16,
                                              const float* s32) {
  int e = v * 4;
  if (e < N8) return ((const float4*)s8)[v];
  if (e < N8 + N16) return ((const float4*)s16)[v - N8 / 4];
  return ((const float4*)s32)[v - (N8 + N16) / 4];
}

__device__ __forceinline__ bool iou_gt04(float4 a, float4 b) {
#pragma clang fp contract(off)
  float areaA = (a.z - a.x) * (a.w - a.y);
  float areaB = (b.z - b.x) * (b.w - b.y);
  float ltx = fmaxf(a.x, b.x);
  float lty = fmaxf(a.y, b.y);
  float rbx = fminf(a.z, b.z);
  float rby = fminf(a.w, b.w);
  float wx = rbx - ltx; wx = wx > 0.0f ? wx : 0.0f;
  float wy = rby - lty; wy = wy > 0.0f ? wy : 0.0f;
  float inter = wx * wy;
  float un = areaA + areaB - inter;
  un = un > 1e-9f ? un : 1e-9f;
  return (inter / un) > 0.4f;
}

__device__ __forceinline__ u64 valid_word(int w, u32 vcnt) {
  int lo = w * 64;
  if ((int)vcnt >= lo + 64) return ~0ull;
  if ((int)vcnt <= lo) return 0ull;
  return (1ull << (vcnt - (u32)lo)) - 1ull;
}

// K1: per-block LDS histogram of positive logits -> plain-stored partial.
// Block 0 zeroes meta/nz for K2/K3 (dispatch-boundary coherent).
__global__ void __launch_bounds__(256) k_hist(
    const float* __restrict__ s8, const float* __restrict__ s16, const float* __restrict__ s32,
    u32* __restrict__ part, u32* __restrict__ meta, u64* __restrict__ nzWords) {
  __shared__ u32 lh[NBINS];
  int t = threadIdx.x, blk = blockIdx.x;
#pragma unroll
  for (int k = 0; k < 16; ++k) lh[k * 256 + t] = 0;
  __syncthreads();
  int v = blk * 256 + t;
  if (v < NTOT4) {
    float4 x = load_logit4(v, s8, s16, s32);
    if (x.x > 0.0f) atomicAdd(&lh[bucket_of(x.x)], 1u);
    if (x.y > 0.0f) atomicAdd(&lh[bucket_of(x.y)], 1u);
    if (x.z > 0.0f) atomicAdd(&lh[bucket_of(x.z)], 1u);
    if (x.w > 0.0f) atomicAdd(&lh[bucket_of(x.w)], 1u);
  }
  __syncthreads();
#pragma unroll
  for (int k = 0; k < 16; ++k) part[blk * NBINS + k * 256 + t] = lh[k * 256 + t];
  if (blk == 0) {
    for (int k = t; k < META_U32; k += 256) meta[k] = 0;
    if (t < NWORDS) nzWords[t] = 0ull;
  }
}

// K2: fused findB + compact + rank + decode (spin-flag handoffs on dedicated lines).
__global__ void __launch_bounds__(256) k_sel(
    const float* __restrict__ s8, const float* __restrict__ s16, const float* __restrict__ s32,
    const float* __restrict__ bb8,  const float* __restrict__ kp8,
    const float* __restrict__ bb16, const float* __restrict__ kp16,
    const float* __restrict__ bb32, const float* __restrict__ kp32,
    const u32* __restrict__ part, u32* red, u32* meta, u64* list,
    float* __restrict__ out) {
  __shared__ __align__(16) char smem[16896];   // hloc 16K + csum overlay / keys 16K
  __shared__ u32 sB, sCnt, sBase;
  __shared__ u32 cnt16[16];
  const int t = threadIdx.x, blk = blockIdx.x;
  const int v = blk * 256 + t;
  const int wave = t >> 6, lane = t & 63;

  // prefetch scores before any spinning
  float4 x = make_float4(-1.f, -1.f, -1.f, -1.f);
  if (v < NTOT4) x = load_logit4(v, s8, s16, s32);

  // ---- stage 1: parallel reduce of 168 partials, 32 blocks x 128 bins ----
  if (blk < NRED) {
    u32* lhs = (u32*)smem;
    int bin = blk * 128 + (t & 127);
    int pp = t >> 7;                 // 0 or 1
    u32 acc = 0;
    for (int p = pp; p < NBLK; p += 2) acc += part[p * NBINS + bin];
    lhs[t] = acc;
    __syncthreads();
    if (t < 128) ast32(&red[blk * 128 + t], lhs[t] + lhs[t + 128]);
    __syncthreads();   // drain sc1 stores (vmcnt) before arriving
    if (t == 0) {
      u32 a = __hip_atomic_fetch_add(&meta[MI_RED], 1u, __ATOMIC_RELAXED,
                                     __HIP_MEMORY_SCOPE_AGENT);
      if (a == NRED - 1) ast32(&meta[MI_REDD], 0xC0DEu);   // done flag, own line
    }
  }

  // ---- stage 2: block 0 finds B and publishes ----
  // B = max bucket with count(>=B) >= TOPK; 0 if fewer than TOPK positives.
  if (blk == 0) {
    if (t == 0)
      while (ald32(&meta[MI_REDD]) != 0xC0DEu) __builtin_amdgcn_s_sleep(2);
    __syncthreads();
    u32* hloc = (u32*)smem;
    u32* csum = (u32*)(smem + 16384);
#pragma unroll
    for (int k = 0; k < 16; ++k) hloc[k * 256 + t] = ald32(&red[k * 256 + t]);
    __syncthreads();
    u32 sum = 0;
    int base = t * 16;
#pragma unroll
    for (int k = 0; k < 16; ++k) sum += hloc[base + k];
    csum[t] = sum;
    __syncthreads();
    for (int off = 1; off < 256; off <<= 1) {   // inclusive suffix scan
      u32 add = (t + off < 256) ? csum[t + off] : 0u;
      __syncthreads();
      csum[t] += add;
      __syncthreads();
    }
    u32 above = (t < 255) ? csum[t + 1] : 0u;
    if (t == 0 && csum[0] < TOPK) ast32(&meta[MI_B], 0xC0DE0000u);   // B=0
    if (csum[t] >= TOPK && above < TOPK) {      // exactly one thread
      u32 cum = above, Bv = (u32)(t * 16);
      for (int b = t * 16 + 15; b >= t * 16; --b) {
        cum += hloc[b];
        if (cum >= TOPK) { Bv = (u32)b; break; }
      }
      ast32(&meta[MI_B], 0xC0DE0000u | Bv);
    }
    __syncthreads();   // keys[] overlay below must not race hloc reads
  }

  // ---- stage 3: spin for B (read-only line), then block-aggregated compact ----
  if (t == 0) {
    u32 pv;
    while (((pv = ald32(&meta[MI_B])) >> 16) != 0xC0DEu) __builtin_amdgcn_s_sleep(4);
    sB = pv & 0xFFFFu;
  }
  __syncthreads();
  const u32 B = sB;
  u32 win = 0;                 // bitmask over the 4 components
  float c[4] = {x.x, x.y, x.z, x.w};
  if (v < NTOT4) {
#pragma unroll
    for (int j = 0; j < 4; ++j)
      if (c[j] > 0.0f && bucket_of(c[j]) >= B) win |= 1u << j;
  }
  u32 wpos[4], wcnt[4];
#pragma unroll
  for (int j = 0; j < 4; ++j) {                 // wave-uniform ballots
    u64 bal = __ballot((win >> j) & 1u);
    wcnt[j] = (u32)__popcll(bal);
    wpos[j] = (u32)__popcll(bal & ((1ull << lane) - 1ull));
  }
  if (lane == 0) {
#pragma unroll
    for (int j = 0; j < 4; ++j) cnt16[wave * 4 + j] = wcnt[j];
  }
  __syncthreads();
  if (t == 0) {                // ONE list-count RMW per block (dedicated line)
    u32 tot = 0, pre[16];
#pragma unroll
    for (int k = 0; k < 16; ++k) { pre[k] = tot; tot += cnt16[k]; }
#pragma unroll
    for (int k = 0; k < 16; ++k) cnt16[k] = pre[k];
    sBase = tot ? atomicAdd(&meta[MI_CNT], tot) : 0u;
  }
  __syncthreads();
#pragma unroll
  for (int j = 0; j < 4; ++j) {
    if ((win >> j) & 1u) {
      u32 dst = sBase + cnt16[wave * 4 + j] + wpos[j];
      if (dst < LIST_CAP) {
        u32 idx = (u32)(v * 4 + j);
        ast64(&list[dst], ((u64)__float_as_uint(c[j]) << 32) | (u64)(~idx));
      }
    }
  }
  __syncthreads();   // drain sc1 list stores before arriving
  if (t == 0) {
    u32 a = __hip_atomic_fetch_add(&meta[MI_CMP], 1u, __ATOMIC_RELAXED,
                                   __HIP_MEMORY_SCOPE_AGENT);
    if (a == NBLK - 1) {       // last arriver: all CNT RMWs complete -> publish cnt
      u32 cc = ald32(&meta[MI_CNT]);
      if (cc > LIST_CAP) cc = LIST_CAP;
      ast32(&meta[MI_CMPD], 0xC0DE0000u | cc);
    }
  }
  if (blk >= RANK_BLKS) return;

  // ---- stage 4: blocks 0..31: O(n^2) exact rank (desc key = stable top-k) + decode ----
  if (t == 0) {
    u32 pv;
    while (((pv = ald32(&meta[MI_CMPD])) >> 16) != 0xC0DEu) __builtin_amdgcn_s_sleep(4);
    sCnt = pv & 0xFFFFu;
  }
  __syncthreads();
  const u32 cnt = sCnt;
  u64* keys = (u64*)smem;
  for (int j = t; j < LIST_CAP; j += 256) keys[j] = (j < (int)cnt) ? ald64(&list[j]) : 0ull;
  __syncthreads();
  if (t >= 64) return;            // 1 active wave/block: LDS pipe uncontended
  int tid = blk * 64 + t;         // candidate id, 0..2047
  if (tid < (int)cnt) {
    u64 my = keys[tid];
    int rank = 0, j = 0;
    for (; j + 4 <= (int)cnt; j += 4)
      rank += (keys[j] > my) + (keys[j + 1] > my) + (keys[j + 2] > my) + (keys[j + 3] > my);
    for (; j < (int)cnt; ++j) rank += (keys[j] > my);
    if (rank < TOPK) {
      float lx = __uint_as_float((u32)(my >> 32));
      float sc = (float)(1.0 / (1.0 + exp(-(double)lx)));   // sigmoid in f64, round once
      u32 idx = ~((u32)my);
      float4 box;
      float kv[10];
      int p, xq, yq;
      float st;
      const float *bb, *kp;
      if (idx < N8) {
        st = 8.f;  p = (int)idx;              xq = p % 480; yq = p / 480; bb = bb8;  kp = kp8;
      } else if (idx < N8 + N16) {
        st = 16.f; p = (int)idx - N8;         xq = p % 240; yq = p / 240; bb = bb16; kp = kp16;
      } else {
        st = 32.f; p = (int)idx - (N8 + N16); xq = p % 120; yq = p / 120; bb = bb32; kp = kp32;
      }
      float cx = (float)xq * st, cy = (float)yq * st;
      {
#pragma clang fp contract(off)
        float d0 = bb[4 * p + 0] * st;
        float d1 = bb[4 * p + 1] * st;
        float d2 = bb[4 * p + 2] * st;
        float d3 = bb[4 * p + 3] * st;
        box.x = cx - d0; box.y = cy - d1; box.z = cx + d2; box.w = cy + d3;
        for (int q = 0; q < 10; ++q)
          kv[q] = kp[10 * p + q] * st + ((q & 1) ? cy : cx);
      }
      ((float4*)out)[rank] = box;
      out[4000 + rank] = sc;
      for (int q = 0; q < 10; ++q) out[5000 + 10 * rank + q] = kv[q];
    }
  } else if (tid < TOPK) {   // unfilled rows: zero
    ((float4*)out)[tid] = make_float4(0.f, 0.f, 0.f, 0.f);
    out[4000 + tid] = 0.f;
    for (int q = 0; q < 10; ++q) out[5000 + 10 * tid + q] = 0.f;
  }
}

// K3: suppression bitmask (63 blocks) + last-arriver greedy NMS + suppressed-row zeroing.
__global__ void __launch_bounds__(256) k_iou_nms(
    const u32* __restrict__ meta_ro, u32* meta, u64* nzWords, u64* mask, float* out) {
  __shared__ __align__(16) char smem[36864];
  __shared__ int isLast;
  __shared__ u32 sPc[16], sOff17[17];
  __shared__ u64 sRem[NWORDS];
  int t = threadIdx.x;
  int blk = blockIdx.x;

  float4* boxes = (float4*)smem;
  for (int r = t; r < TOPK; r += 256) boxes[r] = ((const float4*)out)[r];
  __syncthreads();
  int task = blk * 256 + t;
  if (task < IOU_TASKS) {
    int w = task / 1000;          // 0..15  (wave-mostly-uniform)
    int i = task - w * 1000;      // 0..999 (consecutive per lane -> coalesced)
    float4 a = boxes[i];
    int bse = w * 64;
    int jend = (bse + 64) < TOPK ? (bse + 64) : TOPK;
    u64 bits = 0;
    for (int j = bse; j < jend; ++j)          // boxes[j] wave-broadcast, conflict-free
      if (j > i && iou_gt04(a, boxes[j])) bits |= 1ull << (j - bse);
    ast64(&mask[(u64)w * 1000 + i], bits);    // coalesced (transposed layout)
    if (bits) atomicOr(&nzWords[i >> 6], 1ull << (i & 63));
  }
  __syncthreads();
  if (t == 0)
    isLast = (__hip_atomic_fetch_add(&meta[MI_IOU], 1u, __ATOMIC_RELAXED,
                                     __HIP_MEMORY_SCOPE_AGENT) == (u32)(IOU_BLKS - 1));
  __syncthreads();
  if (!isLast) return;

  // ---- last arriver: exact greedy NMS over nonzero-mask rows only ----
  // Rows with empty suppression sets can't change the removed set -> skipping is exact.
  u32 cnt = meta_ro[MI_CMPD] & 0xFFFFu;   // published by K2; dispatch-boundary coherent
  const u32 vcnt = cnt < TOPK ? cnt : TOPK;
  u32* rows = (u32*)smem;             // up to 1000 row ids (4 KB)
  u64* cache = (u64*)(smem + 4096);   // NMS_CACHE x 16 u64 (32 KB)
  u64 nzv = 0;
  if (t < NWORDS) {
    nzv = ald64(&nzWords[t]) & valid_word(t, vcnt);
    sPc[t] = (u32)__popcll(nzv);
  }
  __syncthreads();
  if (t == 0) {
    u32 o = 0;
    for (int w = 0; w < NWORDS; ++w) { sOff17[w] = o; o += sPc[w]; }
    sOff17[16] = o;
  }
  __syncthreads();
  if (t < NWORDS) {           // expand to ascending row list
    u64 m = nzv;
    u32 o = sOff17[t];
    while (m) { int b = __builtin_ctzll(m); m &= m - 1; rows[o++] = (u32)(t * 64 + b); }
  }
  __syncthreads();
  const int S = (int)sOff17[16];
  const int Sc = S < NMS_CACHE ? S : NMS_CACHE;
  for (int idx = t; idx < Sc * NWORDS; idx += 256) {   // parallel mask prefetch -> LDS
    int s = idx >> 4, w = idx & 15;
    cache[s * NWORDS + w] = ald64(&mask[(u64)w * 1000 + rows[s]]);
  }
  __syncthreads();
  if (t < 64) {               // serial greedy chain, LDS-fed; lane<16 owns word `lane`
    u64 remv = 0;
    for (int s = 0; s < S; ++s) {
      u32 row = rows[s];
      int c = (int)(row >> 6), b = (int)(row & 63);
      u64 remc = __shfl(remv, c);
      if (!((remc >> b) & 1ull)) {   // row still alive -> apply its suppression row
        u64 m = 0;
        if (t < NWORDS)
          m = (s < NMS_CACHE) ? cache[s * NWORDS + t] : ald64(&mask[(u64)t * 1000 + row]);
        remv |= m;
      }
    }
    if (t < NWORDS) sRem[t] = valid_word(t, vcnt) & remv;   // rows to zero
  }
  __syncthreads();
  for (int r = t; r < TOPK; r += 256) {
    if ((sRem[r >> 6] >> (r & 63)) & 1ull) {
      ((float4*)out)[r] = make_float4(0.f, 0.f, 0.f, 0.f);
      out[4000 + r] = 0.f;
      for (int q = 0; q < 10; ++q) out[5000 + 10 * r + q] = 0.f;
    }
  }
}

extern "C" void kernel_launch(void* const* d_in, const int* in_sizes, int n_in,
                              void* d_out, int out_size, void* d_ws, size_t ws_size,
                              hipStream_t stream) {
  const float* s8   = (const float*)d_in[1];
  const float* bb8  = (const float*)d_in[2];
  const float* kp8  = (const float*)d_in[3];
  const float* s16  = (const float*)d_in[4];
  const float* bb16 = (const float*)d_in[5];
  const float* kp16 = (const float*)d_in[6];
  const float* s32  = (const float*)d_in[7];
  const float* bb32 = (const float*)d_in[8];
  const float* kp32 = (const float*)d_in[9];

  char* ws = (char*)d_ws;
  u32* part    = (u32*)(ws + OFF_PART);
  u32* red     = (u32*)(ws + OFF_RED);
  u32* meta    = (u32*)(ws + OFF_META);
  u64* nzWords = (u64*)(ws + OFF_NZ);
  u64* list    = (u64*)(ws + OFF_LIST);
  u64* mask    = (u64*)(ws + OFF_MASK);
  float* out   = (float*)d_out;

  k_hist<<<NBLK, 256, 0, stream>>>(s8, s16, s32, part, meta, nzWords);
  k_sel<<<NBLK, 256, 0, stream>>>(s8, s16, s32, bb8, kp8, bb16, kp16, bb32, kp32,
                                  part, red, meta, list, out);
  k_iou_nms<<<IOU_BLKS, 256, 0, stream>>>(meta, meta, nzWords, mask, out);
}